// Round 6
// baseline (328.475 us; speedup 1.0000x reference)
//
#include <hip/hip_runtime.h>
#include <cmath>

#define D_IN 256
#define H_DIM 128
#define NUM_GRAPHS 1024
#define CHUNK 64
#define MAXSEG 16
#define REC_F 768  // floats per record: ewsum[256], ssum[256], mx[256]

typedef __attribute__((ext_vector_type(8))) __bf16 bf16x8;
typedef __attribute__((ext_vector_type(4))) float f32x4;
typedef __attribute__((ext_vector_type(4))) unsigned short ushort4v;

__device__ inline float b2f(unsigned short u) {
    unsigned int v = ((unsigned int)u) << 16;
    return __builtin_bit_cast(float, v);
}

// ---------------------------------------------------------------------------
// Pack W1 (f32 [256][128]) into bf16 MFMA B-fragment order.
// B-frag for mfma_f32_16x16x32_bf16: lane l holds B[k][n], n = nt*16 + (l&15),
// k = ks*32 + (l>>4)*8 + i. packed[((nt*8+ks)*64 + l)*8 + i]
// ---------------------------------------------------------------------------
__global__ void pack_w1(const float* __restrict__ W1, ushort* __restrict__ packed) {
    int tid = blockIdx.x * 256 + threadIdx.x;
    if (tid >= 8 * 8 * 64) return;
    int nt = tid >> 9;
    int ks = (tid >> 6) & 7;
    int l = tid & 63;
    int col = nt * 16 + (l & 15);
    int kbase = ks * 32 + ((l >> 4) & 3) * 8;
#pragma unroll
    for (int i = 0; i < 8; ++i) {
        float v = W1[(size_t)(kbase + i) * H_DIM + col];
        __bf16 b = (__bf16)v;
        packed[(size_t)tid * 8 + i] = __builtin_bit_cast(unsigned short, b);
    }
}

// ---------------------------------------------------------------------------
// Fused kernel: one 64-row tile per block (7813 blocks -> ~30/CU).
// Wave w owns rows [w*16, w*16+16): hoisted f32 loads -> bf16 cvt -> stage to
// private LDS slice -> MFMA scores -> weights stay in-wave -> pool from LDS.
// Barriers only for segment scan + per-segment flush.
// ---------------------------------------------------------------------------
__global__ __launch_bounds__(256) void fused_kernel(
    const float* __restrict__ x, const ushort* __restrict__ w1p,
    const float* __restrict__ b1, const float* __restrict__ W2,
    const float* __restrict__ b2, const int* __restrict__ batch,
    float* __restrict__ recs, int2* __restrict__ hdr,
    float* __restrict__ zpart, int N) {
    int tid = threadIdx.x;
    int l = tid & 63;
    int w = tid >> 6;
    int r16 = l & 15;
    int kg = l >> 4;
    int blk = blockIdx.x;
    long long base = (long long)blk * CHUNK;
    int chunkN = (int)min((long long)CHUNK, (long long)N - base);

    __shared__ ushort sx[4][16 * D_IN];  // 32 KB, per-wave private bf16 slices
    __shared__ int sbatch[CHUNK];
    __shared__ int seglist[MAXSEG + 1];
    __shared__ int snseg;
    __shared__ float red[4][3][256];  // 12 KB flush staging

    // ---- issue the long-latency x loads FIRST ----
    int wr0 = w * 16;  // wave's first row within chunk
    long long arow = base + wr0 + r16;
    if (arow >= N) arow = N - 1;
    const float* xptr = x + arow * D_IN + kg * 8;

    f32x4 xv[16];
#pragma unroll
    for (int ks = 0; ks < 8; ++ks) {
        xv[2 * ks] = *(const f32x4*)(xptr + ks * 32);
        xv[2 * ks + 1] = *(const f32x4*)(xptr + ks * 32 + 4);
    }

    // epilogue weights (L2-hot after first blocks)
    float w2v[8], b1v[8];
#pragma unroll
    for (int nt = 0; nt < 8; ++nt) {
        int c = nt * 16 + r16;
        w2v[nt] = W2[c];
        b1v[nt] = b1[c];
    }
    float bb = b2[0];

    // ---- batch slice + segment scan (overlaps x-load latency) ----
    if (tid < MAXSEG) hdr[blk * MAXSEG + tid] = make_int2(-1, 0);
    if (tid < chunkN) sbatch[tid] = batch[base + tid];
    __syncthreads();
    if (tid < 64) {
        bool flag = (l < chunkN) && (l == 0 || sbatch[l] != sbatch[l - 1]);
        unsigned long long m = __ballot(flag);
        if (l == 0) {
            int nseg = 0;
            while (m) {
                int b = __ffsll(m) - 1;
                if (nseg < MAXSEG) seglist[nseg] = b;
                nseg++;
                m &= m - 1;
            }
            if (nseg > MAXSEG) nseg = MAXSEG;
            snseg = nseg;
            seglist[nseg] = chunkN;
        }
    }
    __syncthreads();
    int nseg = snseg;

    // ---- cvt to bf16, stage into private LDS slice (swizzled) ----
    bf16x8 af[8];
#pragma unroll
    for (int ks = 0; ks < 8; ++ks) {
#pragma unroll
        for (int i = 0; i < 4; ++i) {
            af[ks][i] = (__bf16)xv[2 * ks][i];
            af[ks][i + 4] = (__bf16)xv[2 * ks + 1][i];
        }
        unsigned a = ((unsigned)(r16 * 512 + ks * 64 + kg * 16)) ^ ((unsigned)(r16 & 7) << 4);
        *(bf16x8*)((char*)sx[w] + a) = af[ks];
    }

    // ---- MFMA scores ----
    f32x4 acc[8] = {};
#pragma unroll
    for (int ks = 0; ks < 8; ++ks) {
#pragma unroll
        for (int nt = 0; nt < 8; ++nt) {
            bf16x8 bfw = *(const bf16x8*)(w1p + ((size_t)(nt * 8 + ks) * 64 + l) * 8);
            acc[nt] = __builtin_amdgcn_mfma_f32_16x16x32_bf16(af[ks], bfw, acc[nt], 0, 0, 0);
        }
    }
    // epilogue: butterfly leaves row score in all 16 lanes of each kg group
    float e[4];
    float zacc = 0.f;
#pragma unroll
    for (int reg = 0; reg < 4; ++reg) {
        float p = 0.f;
#pragma unroll
        for (int nt = 0; nt < 8; ++nt) {
            float h = acc[nt][reg] + b1v[nt];
            p += fmaxf(h, 0.f) * w2v[nt];
        }
        p += __shfl_xor(p, 1, 64);
        p += __shfl_xor(p, 2, 64);
        p += __shfl_xor(p, 4, 64);
        p += __shfl_xor(p, 8, 64);
        int rowc = wr0 + kg * 4 + reg;
        e[reg] = (rowc < chunkN) ? __expf(p + bb) : 0.f;
        zacc += e[reg];  // replicated 16x per row; /16 at the end (exact)
    }

    // ---- POOL from private LDS + FLUSH per segment (uniform loop) ----
    f32x4 asum = {0.f, 0.f, 0.f, 0.f};
    f32x4 ssum = {0.f, 0.f, 0.f, 0.f};
    f32x4 mx = {-INFINITY, -INFINITY, -INFINITY, -INFINITY};

    for (int sg = 0; sg < nseg; ++sg) {
        int sStart = seglist[sg];
        int sEnd = seglist[sg + 1];
#pragma unroll
        for (int j = 0; j < 16; ++j) {
            int i = wr0 + j;
            float wj = __shfl(e[j & 3], (j >> 2) << 4, 64);
            bool in = (i >= sStart) && (i < sEnd);
            unsigned a = ((unsigned)(j * 512 + l * 8)) ^ ((unsigned)(j & 7) << 4);
            ushort4v hv = *(const ushort4v*)((const char*)sx[w] + a);
            float wje = in ? wj : 0.f;
#pragma unroll
            for (int c = 0; c < 4; ++c) {
                float v = b2f(hv[c]);
                asum[c] += v * wje;
                ssum[c] += in ? v : 0.f;
                mx[c] = fmaxf(mx[c], in ? v : -INFINITY);
            }
        }
        // flush (block-uniform): reduce 4 waves via LDS, write record
        *(f32x4*)&red[w][0][l * 4] = asum;
        *(f32x4*)&red[w][1][l * 4] = ssum;
        *(f32x4*)&red[w][2][l * 4] = mx;
        __syncthreads();
        {
            float aa = red[0][0][tid] + red[1][0][tid] +
                       red[2][0][tid] + red[3][0][tid];
            float s2 = red[0][1][tid] + red[1][1][tid] +
                       red[2][1][tid] + red[3][1][tid];
            float m2 = fmaxf(fmaxf(red[0][2][tid], red[1][2][tid]),
                             fmaxf(red[2][2][tid], red[3][2][tid]));
            float* rb = recs + (size_t)(blk * MAXSEG + sg) * REC_F;
            rb[tid] = aa;
            rb[256 + tid] = s2;
            rb[512 + tid] = m2;
        }
        if (tid == 0)
            hdr[blk * MAXSEG + sg] = make_int2(sbatch[sStart], sEnd - sStart);
        __syncthreads();
#pragma unroll
        for (int c = 0; c < 4; ++c) {
            asum[c] = 0.f;
            ssum[c] = 0.f;
            mx[c] = -INFINITY;
        }
    }

    // per-wave z partial (each row counted 16x; /16 exact)
    zacc += __shfl_xor(zacc, 1, 64);
    zacc += __shfl_xor(zacc, 2, 64);
    zacc += __shfl_xor(zacc, 4, 64);
    zacc += __shfl_xor(zacc, 8, 64);
    zacc += __shfl_xor(zacc, 16, 64);
    zacc += __shfl_xor(zacc, 32, 64);
    if (l == 0) zpart[blk * 4 + w] = zacc * 0.0625f;
}

// ---------------------------------------------------------------------------
// Reduce all z partials to a single 1/Z.
// ---------------------------------------------------------------------------
__global__ __launch_bounds__(256) void zreduce_kernel(
    const float* __restrict__ zpart, int n, float* __restrict__ MZ) {
    int tid = threadIdx.x;
    float z = 0.f;
    for (int i = tid; i < n; i += 256) z += zpart[i];
    __shared__ float sz[256];
    sz[tid] = z;
    __syncthreads();
    for (int off = 128; off > 0; off >>= 1) {
        if (tid < off) sz[tid] += sz[tid + off];
        __syncthreads();
    }
    if (tid == 0) MZ[0] = 1.f / sz[0];
}

// ---------------------------------------------------------------------------
__device__ inline int lower_bound_i(const int* __restrict__ arr, int n, int val) {
    int lo = 0, hi = n;
    while (lo < hi) {
        int mid = (lo + hi) >> 1;
        if (arr[mid] < val) lo = mid + 1; else hi = mid;
    }
    return lo;
}

// One block per graph: merge partial records, normalize by Z, write output.
__global__ __launch_bounds__(256) void combine_kernel(
    const float* __restrict__ recs, const int2* __restrict__ hdr,
    const float* __restrict__ MZ,
    const int* __restrict__ batch, int N, float* __restrict__ out) {
    int g = blockIdx.x;
    int tid = threadIdx.x;
    float invZ = MZ[0];

    __shared__ int sb[2];
    if (tid < 2) sb[tid] = lower_bound_i(batch, N, g + tid);
    __syncthreads();
    int start = sb[0], end = sb[1];

    float ew = 0.f, ss = 0.f, mxv = -INFINITY;
    int cnt = 0;
    if (end > start) {
        int b0 = start / CHUNK, b1 = (end - 1) / CHUNK;
        for (int b = b0; b <= b1; ++b) {
            for (int si = 0; si < MAXSEG; ++si) {
                int2 h = hdr[b * MAXSEG + si];
                if (h.x == g) {
                    const float* rb = recs + (size_t)(b * MAXSEG + si) * REC_F;
                    ew += rb[tid];
                    ss += rb[256 + tid];
                    mxv = fmaxf(mxv, rb[512 + tid]);
                    cnt += h.y;
                }
            }
        }
    }
    size_t ob = (size_t)g * (3 * D_IN);
    out[ob + tid] = ew * invZ;
    out[ob + D_IN + tid] = (cnt > 0) ? mxv : 0.f;
    out[ob + 2 * D_IN + tid] = ss / (float)max(cnt, 1);
}

// ---------------------------------------------------------------------------
extern "C" void kernel_launch(void* const* d_in, const int* in_sizes, int n_in,
                              void* d_out, int out_size, void* d_ws, size_t ws_size,
                              hipStream_t stream) {
    const float* x = (const float*)d_in[0];
    const float* W1 = (const float*)d_in[1];
    const float* b1 = (const float*)d_in[2];
    const float* W2 = (const float*)d_in[3];
    const float* b2 = (const float*)d_in[4];
    const int* batch = (const int*)d_in[5];
    int N = in_sizes[0] / D_IN;
    float* out = (float*)d_out;
    int NB = (N + CHUNK - 1) / CHUNK;

    char* ws = (char*)d_ws;
    size_t off = 0;
    ushort* w1p = (ushort*)(ws + off);
    off += 8 * 8 * 64 * 8 * sizeof(ushort);  // 64 KB
    off = (off + 255) & ~(size_t)255;
    float* recs = (float*)(ws + off);
    off += (size_t)NB * MAXSEG * REC_F * sizeof(float);  // ~384 MB
    off = (off + 255) & ~(size_t)255;
    int2* hdr = (int2*)(ws + off);
    off += (size_t)NB * MAXSEG * sizeof(int2);  // ~1 MB
    off = (off + 255) & ~(size_t)255;
    float* zpart = (float*)(ws + off);
    off += (size_t)NB * 4 * sizeof(float);
    off = (off + 255) & ~(size_t)255;
    float* MZ = (float*)(ws + off);
    off += 256;

    pack_w1<<<16, 256, 0, stream>>>(W1, w1p);
    fused_kernel<<<NB, 256, 0, stream>>>(x, w1p, b1, W2, b2, batch,
                                         recs, hdr, zpart, N);
    zreduce_kernel<<<1, 256, 0, stream>>>(zpart, NB * 4, MZ);
    combine_kernel<<<NUM_GRAPHS, 256, 0, stream>>>(recs, hdr, MZ, batch, N, out);
}

// Round 7
// 172.808 us; speedup vs baseline: 1.9008x; 1.9008x over previous
//
#include <hip/hip_runtime.h>
#include <cmath>

#define D_IN 256
#define H_DIM 128
#define NUM_GRAPHS 1024
#define CHUNK 64
#define MAXSEG 4
#define REC_F 768  // floats per record: ewsum[256], ssum[256], mx[256]

typedef __attribute__((ext_vector_type(8))) __bf16 bf16x8;
typedef __attribute__((ext_vector_type(4))) float f32x4;
typedef __attribute__((ext_vector_type(4))) unsigned short ushort4v;

__device__ inline float b2f(unsigned short u) {
    unsigned int v = ((unsigned int)u) << 16;
    return __builtin_bit_cast(float, v);
}

// ---------------------------------------------------------------------------
// Pack W1 (f32 [256][128]) into bf16 MFMA B-fragment order.
// B-frag for mfma_f32_16x16x32_bf16: lane l holds B[k][n], n = nt*16 + (l&15),
// k = ks*32 + (l>>4)*8 + i. packed[((nt*8+ks)*64 + l)*8 + i]
// ---------------------------------------------------------------------------
__global__ void pack_w1(const float* __restrict__ W1, ushort* __restrict__ packed) {
    int tid = blockIdx.x * 256 + threadIdx.x;
    if (tid >= 8 * 8 * 64) return;
    int nt = tid >> 9;
    int ks = (tid >> 6) & 7;
    int l = tid & 63;
    int col = nt * 16 + (l & 15);
    int kbase = ks * 32 + ((l >> 4) & 3) * 8;
#pragma unroll
    for (int i = 0; i < 8; ++i) {
        float v = W1[(size_t)(kbase + i) * H_DIM + col];
        __bf16 b = (__bf16)v;
        packed[(size_t)tid * 8 + i] = __builtin_bit_cast(unsigned short, b);
    }
}

// ---------------------------------------------------------------------------
// Fused kernel. One 64-row chunk per block. nt-SPLIT decomposition:
// wave w computes ALL 64 rows over H-cols [w*32, w*32+32) with its 16 KB of
// W1 held in REGISTERS (loaded once: kills the per-wave 64KB L2 chain).
// x tile staged to LDS bf16 (XOR-swizzled); partial scores reduced via LDS.
// Exactly 2 barriers per block.
// ---------------------------------------------------------------------------
__global__ __launch_bounds__(256) void fused_kernel(
    const float* __restrict__ x, const ushort* __restrict__ w1p,
    const float* __restrict__ b1, const float* __restrict__ W2,
    const float* __restrict__ b2, const int* __restrict__ batch,
    float* __restrict__ recs, int2* __restrict__ hdr,
    float* __restrict__ zpart, int N) {
    int tid = threadIdx.x;
    int l = tid & 63;
    int w = tid >> 6;
    int r16 = l & 15;
    int kg = l >> 4;
    int blk = blockIdx.x;
    long long base = (long long)blk * CHUNK;
    int chunkN = (int)min((long long)CHUNK, (long long)N - base);

    __shared__ ushort sx[CHUNK * D_IN];  // 32 KB bf16 tile, swizzled g^=(row&7)
    __shared__ float pscore[CHUNK][4];   // [row][wave] partial scores
    __shared__ int sbatch[CHUNK];
    __shared__ int seglist[MAXSEG + 1];
    __shared__ int seggid[MAXSEG];
    __shared__ int snseg;

    // ---- wave 0: batch values (issued early, consumed after stage) ----
    int bval = 0;
    if (w == 0) {
        long long bi = base + l;
        bval = (bi < N) ? batch[bi] : -1;
        sbatch[l] = bval;
    }

    // ---- per-wave W1 slice -> registers (16 independent L2 loads) ----
    bf16x8 breg0[8], breg1[8];
#pragma unroll
    for (int ks = 0; ks < 8; ++ks) {
        breg0[ks] = *(const bf16x8*)(w1p + ((size_t)((w * 2) * 8 + ks) * 64 + l) * 8);
        breg1[ks] = *(const bf16x8*)(w1p + ((size_t)((w * 2 + 1) * 8 + ks) * 64 + l) * 8);
    }

    // ---- STAGE: thread t -> row t>>2, granules g=(t&3)+4j; all 16 loads hoisted ----
    {
        int row = tid >> 2;
        long long grow = base + row;
        if (grow >= N) grow = N - 1;
        const float* xr = x + grow * D_IN;
        int gb = tid & 3;
        f32x4 xv[16];
#pragma unroll
        for (int j = 0; j < 8; ++j) {
            int g = gb + 4 * j;
            xv[2 * j] = *(const f32x4*)(xr + g * 8);
            xv[2 * j + 1] = *(const f32x4*)(xr + g * 8 + 4);
        }
        unsigned rowswz = (unsigned)(row & 7) << 4;
#pragma unroll
        for (int j = 0; j < 8; ++j) {
            int g = gb + 4 * j;
            bf16x8 pk;
#pragma unroll
            for (int i = 0; i < 4; ++i) {
                pk[i] = (__bf16)xv[2 * j][i];
                pk[i + 4] = (__bf16)xv[2 * j + 1][i];
            }
            unsigned addr = ((unsigned)(row * 512 + g * 16)) ^ rowswz;
            *(bf16x8*)((char*)sx + addr) = pk;
        }
    }

    // epilogue constants for this wave's 32 cols
    float w2v[2], b1v[2];
#pragma unroll
    for (int q = 0; q < 2; ++q) {
        int c = (w * 2 + q) * 16 + r16;
        w2v[q] = W2[c];
        b1v[q] = b1[c];
    }
    float bb = b2[0];

    // ---- wave 0: segment scan (overlaps other waves' staging) ----
    if (w == 0) {
        int prev = __shfl_up(bval, 1, 64);
        bool flag = (l < chunkN) && (l == 0 || bval != prev);
        unsigned long long m = __ballot(flag);
        if (l == 0) {
            int ns = 0;
            while (m && ns < MAXSEG) {
                int b = __ffsll(m) - 1;
                seglist[ns] = b;
                seggid[ns] = sbatch[b];
                ns++;
                m &= m - 1;
            }
            snseg = ns;
            seglist[ns] = chunkN;
        }
    }
    __syncthreads();  // barrier A: tile + seglist ready

    // ---- MFMA: acc[mt][nt'] over all 4 row-tiles x this wave's 2 n-tiles ----
    f32x4 acc[4][2] = {};
#pragma unroll
    for (int ks = 0; ks < 8; ++ks) {
#pragma unroll
        for (int mt = 0; mt < 4; ++mt) {
            int row = mt * 16 + r16;
            unsigned addr = ((unsigned)(row * 512 + ks * 64 + kg * 16)) ^
                            ((unsigned)(row & 7) << 4);
            bf16x8 af = *(const bf16x8*)((const char*)sx + addr);
            acc[mt][0] = __builtin_amdgcn_mfma_f32_16x16x32_bf16(af, breg0[ks], acc[mt][0], 0, 0, 0);
            acc[mt][1] = __builtin_amdgcn_mfma_f32_16x16x32_bf16(af, breg1[ks], acc[mt][1], 0, 0, 0);
        }
    }
    // partial-score epilogue: sum over this wave's 32 cols
#pragma unroll
    for (int mt = 0; mt < 4; ++mt) {
#pragma unroll
        for (int reg = 0; reg < 4; ++reg) {
            float p = fmaxf(acc[mt][0][reg] + b1v[0], 0.f) * w2v[0] +
                      fmaxf(acc[mt][1][reg] + b1v[1], 0.f) * w2v[1];
            p += __shfl_xor(p, 1, 64);
            p += __shfl_xor(p, 2, 64);
            p += __shfl_xor(p, 4, 64);
            p += __shfl_xor(p, 8, 64);
            if (r16 == 0) pscore[mt * 16 + kg * 4 + reg][w] = p;
        }
    }
    __syncthreads();  // barrier B: pscore complete

    // ---- e per lane (each wave redundantly holds all 64 rows' weights) ----
    f32x4 ps = *(const f32x4*)&pscore[l][0];
    float e_l = (l < chunkN) ? __expf(ps[0] + ps[1] + ps[2] + ps[3] + bb) : 0.f;

    if (w == 0) {
        float z = e_l;
        z += __shfl_xor(z, 1, 64);
        z += __shfl_xor(z, 2, 64);
        z += __shfl_xor(z, 4, 64);
        z += __shfl_xor(z, 8, 64);
        z += __shfl_xor(z, 16, 64);
        z += __shfl_xor(z, 32, 64);
        if (l == 0) zpart[blk] = z;
    }

    int nseg = snseg;

    // ---- POOL: wave w pools rows [w*16, w*16+16), lane l cols [l*4, l*4+4) ----
    f32x4 asum = {0.f, 0.f, 0.f, 0.f};
    f32x4 ssum = {0.f, 0.f, 0.f, 0.f};
    f32x4 mx = {-INFINITY, -INFINITY, -INFINITY, -INFINITY};

    for (int sg = 0; sg < nseg; ++sg) {
        int sStart = seglist[sg];
        int sEnd = seglist[sg + 1];
#pragma unroll
        for (int j = 0; j < 16; ++j) {
            int row = w * 16 + j;
            float wj = __shfl(e_l, row, 64);
            bool in = (row >= sStart) && (row < sEnd);
            unsigned addr = ((unsigned)(row * 512 + l * 8)) ^
                            ((unsigned)(row & 7) << 4);
            ushort4v hv = *(const ushort4v*)((const char*)sx + addr);
            float wje = in ? wj : 0.f;
#pragma unroll
            for (int c = 0; c < 4; ++c) {
                float v = b2f(hv[c]);
                asum[c] += v * wje;
                ssum[c] += in ? v : 0.f;
                mx[c] = fmaxf(mx[c], in ? v : -INFINITY);
            }
        }
        // per-wave flush: no barrier needed
        float* rb = recs + ((size_t)(blk * MAXSEG + sg) * 4 + w) * REC_F;
        *(f32x4*)(rb + l * 4) = asum;
        *(f32x4*)(rb + 256 + l * 4) = ssum;
        *(f32x4*)(rb + 512 + l * 4) = mx;
        if (w == 0 && l == 0)
            hdr[blk * MAXSEG + sg] = make_int2(seggid[sg], sEnd - sStart);
#pragma unroll
        for (int c = 0; c < 4; ++c) {
            asum[c] = 0.f;
            ssum[c] = 0.f;
            mx[c] = -INFINITY;
        }
    }
    if (w == 0 && l == 0) {
        for (int sg = nseg; sg < MAXSEG; ++sg)
            hdr[blk * MAXSEG + sg] = make_int2(-1, 0);
    }
}

// ---------------------------------------------------------------------------
__global__ __launch_bounds__(256) void zreduce_kernel(
    const float* __restrict__ zpart, int n, float* __restrict__ MZ) {
    int tid = threadIdx.x;
    float z = 0.f;
    for (int i = tid; i < n; i += 256) z += zpart[i];
    __shared__ float sz[256];
    sz[tid] = z;
    __syncthreads();
    for (int off = 128; off > 0; off >>= 1) {
        if (tid < off) sz[tid] += sz[tid + off];
        __syncthreads();
    }
    if (tid == 0) MZ[0] = 1.f / sz[0];
}

// ---------------------------------------------------------------------------
__device__ inline int lower_bound_i(const int* __restrict__ arr, int n, int val) {
    int lo = 0, hi = n;
    while (lo < hi) {
        int mid = (lo + hi) >> 1;
        if (arr[mid] < val) lo = mid + 1; else hi = mid;
    }
    return lo;
}

// One block per graph; wave w consumes wave-w records (4x fewer serial loads).
__global__ __launch_bounds__(256) void combine_kernel(
    const float* __restrict__ recs, const int2* __restrict__ hdr,
    const float* __restrict__ MZ,
    const int* __restrict__ batch, int N, float* __restrict__ out) {
    int g = blockIdx.x;
    int tid = threadIdx.x;
    int w = tid >> 6;
    int l = tid & 63;
    float invZ = MZ[0];

    __shared__ int sb[2];
    if (tid < 2) sb[tid] = lower_bound_i(batch, N, g + tid);
    __syncthreads();
    int start = sb[0], end = sb[1];

    f32x4 ew = {0.f, 0.f, 0.f, 0.f};
    f32x4 ss = {0.f, 0.f, 0.f, 0.f};
    f32x4 mxv = {-INFINITY, -INFINITY, -INFINITY, -INFINITY};
    int cnt = 0;
    if (end > start) {
        int b0 = start >> 6, b1 = (end - 1) >> 6;
        for (int b = b0; b <= b1; ++b) {
#pragma unroll
            for (int sg = 0; sg < MAXSEG; ++sg) {
                int2 h = hdr[b * MAXSEG + sg];
                if (h.x == g) {
                    const float* rb = recs + ((size_t)(b * MAXSEG + sg) * 4 + w) * REC_F;
                    f32x4 a = *(const f32x4*)(rb + l * 4);
                    f32x4 s = *(const f32x4*)(rb + 256 + l * 4);
                    f32x4 m = *(const f32x4*)(rb + 512 + l * 4);
#pragma unroll
                    for (int c = 0; c < 4; ++c) {
                        ew[c] += a[c];
                        ss[c] += s[c];
                        mxv[c] = fmaxf(mxv[c], m[c]);
                    }
                    cnt += h.y;
                }
            }
        }
    }

    __shared__ float red[4][3][256];
    *(f32x4*)&red[w][0][l * 4] = ew;
    *(f32x4*)&red[w][1][l * 4] = ss;
    *(f32x4*)&red[w][2][l * 4] = mxv;
    __syncthreads();
    float ewt = red[0][0][tid] + red[1][0][tid] + red[2][0][tid] + red[3][0][tid];
    float sst = red[0][1][tid] + red[1][1][tid] + red[2][1][tid] + red[3][1][tid];
    float mxt = fmaxf(fmaxf(red[0][2][tid], red[1][2][tid]),
                      fmaxf(red[2][2][tid], red[3][2][tid]));

    size_t ob = (size_t)g * (3 * D_IN);
    out[ob + tid] = ewt * invZ;
    out[ob + D_IN + tid] = (end > start) ? mxt : 0.f;
    out[ob + 2 * D_IN + tid] = sst / (float)max(cnt, 1);
}

// ---------------------------------------------------------------------------
extern "C" void kernel_launch(void* const* d_in, const int* in_sizes, int n_in,
                              void* d_out, int out_size, void* d_ws, size_t ws_size,
                              hipStream_t stream) {
    const float* x = (const float*)d_in[0];
    const float* W1 = (const float*)d_in[1];
    const float* b1 = (const float*)d_in[2];
    const float* W2 = (const float*)d_in[3];
    const float* b2 = (const float*)d_in[4];
    const int* batch = (const int*)d_in[5];
    int N = in_sizes[0] / D_IN;
    float* out = (float*)d_out;
    int NB = (N + CHUNK - 1) / CHUNK;

    char* ws = (char*)d_ws;
    size_t off = 0;
    ushort* w1p = (ushort*)(ws + off);
    off += 8 * 8 * 64 * 8 * sizeof(ushort);  // 64 KB
    off = (off + 255) & ~(size_t)255;
    float* recs = (float*)(ws + off);
    off += (size_t)NB * MAXSEG * 4 * REC_F * sizeof(float);  // ~384 MB
    off = (off + 255) & ~(size_t)255;
    int2* hdr = (int2*)(ws + off);
    off += (size_t)NB * MAXSEG * sizeof(int2);
    off = (off + 255) & ~(size_t)255;
    float* zpart = (float*)(ws + off);
    off += (size_t)NB * sizeof(float);
    off = (off + 255) & ~(size_t)255;
    float* MZ = (float*)(ws + off);
    off += 256;

    pack_w1<<<16, 256, 0, stream>>>(W1, w1p);
    fused_kernel<<<NB, 256, 0, stream>>>(x, w1p, b1, W2, b2, batch,
                                         recs, hdr, zpart, N);
    zreduce_kernel<<<1, 256, 0, stream>>>(zpart, NB, MZ);
    combine_kernel<<<NUM_GRAPHS, 256, 0, stream>>>(recs, hdr, MZ, batch, N, out);
}